// Round 2
// baseline (796.997 us; speedup 1.0000x reference)
//
#include <hip/hip_runtime.h>

// 2-layer LSTM (PyTorch gate order i,f,g,o), L=2048, B=512, INPUT=78, H=4.
//
// Kernel 1 (memory-bound, unchanged since R4): LDS-staged input projection.
//   Output xg0[t][b][j][g] prescaled by +-log2e (g gate: +2log2e), bias1
//   (prescaled) at ws[0..15], laid out [j*4+g].
// Kernel 2 (latency-bound recurrence, R7 restructure): 16 lanes per
//   (batch, layer) -- lane = b2*32 + layer*16 + j*4 + g. One gate per lane:
//   1 sigmoid-form activation + 1 tanh(c) per step (4 trans ops).
//   R7: ds_swizzle removed from the critical path.
//   - Within-row h broadcast (h[j^m]) via 2-deep DPP compositions on the
//     VALU pipe: ^4 = half_mirror(^7) o quad_perm(^3), ^8 = mirror(^15) o
//     half_mirror, ^12 = mirror o quad_perm. 5 DPPs, ~4cy each (was
//     ds_swizzle, ~120cy LDS latency).
//   - Layer skew deepened 1 -> 2: layer1 at iter i computes t=i-2, consuming
//     y0 shipped (4x ds_swizzle ^16 applied to A_m) at iter i-2. The LDS
//     latency gets a full iteration (~300cy) of slack -> fully hidden.
//     Ships double-buffered in Bb0/Bb1 (statically named; pair-unrolled
//     loop keeps buf[] indices compile-time, no scratch).
//   - B-side partial sum (preP) computed from step start (B known early),
//     so the critical path runs only through the A fma tree.
//   Cell state kept prescaled: cs = 2*log2e*c. Layer1 lanes stream their own
//   prescaled bias dword (stride 0). 2 batches/wave -> 256 blocks = every CU.
//
// ws: [0,64) bias1_scaled | [20480 B, 20480+64MiB) xg0.

#define LSEQ  2048
#define BATCH 512
#define NIN   78
#define LOG2E 1.4426950408889634f

#define WS_BIAS_F  0
#define WS_XG_F    5120
#define XG_BYTES   ((unsigned)LSEQ * BATCH * 16u * 4u)

#define RPB  128
#define TPB1 128

__device__ __forceinline__ float rcp_(float x) { return __builtin_amdgcn_rcpf(x); }
__device__ __forceinline__ float ex2_(float x) { return __builtin_amdgcn_exp2f(x); }

template<int CTRL>
__device__ __forceinline__ float dppf(float x) {
  int r = __builtin_amdgcn_update_dpp(0, __builtin_bit_cast(int, x), CTRL, 0xf, 0xf, false);
  return __builtin_bit_cast(float, r);
}
template<int PAT>
__device__ __forceinline__ float swzf(float x) {
  int r = __builtin_amdgcn_ds_swizzle(__builtin_bit_cast(int, x), PAT);
  return __builtin_bit_cast(float, r);
}

// DPP ctrl values
#define QP_REV  0x1B   // quad_perm [3,2,1,0]  : lane ^ 3
#define ROW_HM  0x141  // row_half_mirror      : lane ^ 7
#define ROW_MIR 0x140  // row_mirror           : lane ^ 15

// ---------------- kernel 1: input projection (LDS-staged) ----------------
__global__ __launch_bounds__(TPB1) void xg_kernel(
    const float* __restrict__ x, const float* __restrict__ Wih0,
    const float* __restrict__ bih0, const float* __restrict__ bhh0,
    const float* __restrict__ bih1, const float* __restrict__ bhh1,
    float* __restrict__ ws)
{
  __shared__ float xs[RPB * NIN];
  const int tid = threadIdx.x;
  const int r0  = blockIdx.x * RPB;

  if (blockIdx.x == 0 && tid < 16) {       // prescaled layer-1 bias [j*4+g]
    const int j = tid >> 2, g = tid & 3, row = j + 4 * g;
    const float s = (g == 2) ? 2.f * LOG2E : -LOG2E;
    ws[WS_BIAS_F + tid] = s * (bih1[row] + bhh1[row]);
  }

  const float4* gx = (const float4*)(x + (size_t)r0 * NIN);
  float4* ls = (float4*)xs;
  for (int i = tid; i < RPB * NIN / 4; i += TPB1) ls[i] = gx[i];
  __syncthreads();

  const float* xr = xs + tid * NIN;
  float acc[16];
#pragma unroll
  for (int row = 0; row < 16; ++row) acc[row] = bih0[row] + bhh0[row];
  for (int k = 0; k < NIN; ++k) {
    const float xk = xr[k];
#pragma unroll
    for (int row = 0; row < 16; ++row) acc[row] += xk * Wih0[row * NIN + k];
  }
#pragma unroll
  for (int row = 0; row < 16; ++row) {
    const float s = ((row >> 2) == 2) ? 2.f * LOG2E : -LOG2E;
    acc[row] *= s;
  }
  float* o = ws + WS_XG_F + (size_t)(r0 + tid) * 16;
#pragma unroll
  for (int j = 0; j < 4; ++j) {
    float4 v = make_float4(acc[j], acc[j + 4], acc[j + 8], acc[j + 12]);
    *(float4*)(o + j * 4) = v;
  }
}

// ---------------- kernel 2: recurrence (16 lanes per batch-layer) --------
__global__ __launch_bounds__(64) void lstm_rec(
    const float* __restrict__ wsr,
    const int* __restrict__ lens,
    const float* __restrict__ Whh0, const float* __restrict__ Whh1,
    const float* __restrict__ Wih1,
    float* __restrict__ out)
{
  const int lane  = threadIdx.x;
  const int g     = lane & 3;          // gate: 0=i 1=f 2=g 3=o
  const int j     = (lane >> 2) & 3;   // hidden unit
  const int layer = (lane >> 4) & 1;
  const int b     = blockIdx.x * 2 + (lane >> 5);

  const float sg = (g == 2) ? 2.f * LOG2E : -LOG2E;   // pre-activation scale
  // act = ka*rcp(1+exp2(P)) + kb : sigmoid lanes -> sigma; g lane -> 2log2e*tanh
  const float ka = (g == 2) ? -4.f * LOG2E : 1.f;
  const float kb = (g == 2) ?  2.f * LOG2E : 0.f;

  const int row4 = (g * 4 + j) * 4;    // PyTorch row = gate*4 + unit
  const float* whh = layer ? Whh1 : Whh0;
  float wA[4], wB[4];
#pragma unroll
  for (int m = 0; m < 4; ++m) {        // A_m = h[j^m]
    wA[m] = sg * whh[row4 + (j ^ m)];
    wB[m] = layer ? sg * Wih1[row4 + (j ^ m)] : 0.f;
  }
  const int len = lens[b];

  // layer0 lanes stream xg0[t][b][j*4+g]; layer1 lanes "stream" their own
  // prescaled bias dword (stride 0) so the dot base needs no per-iter select.
  unsigned ofs = layer ? (unsigned)((j * 4 + g) * 4)
                       : (unsigned)(WS_XG_F * 4 + (b * 16 + j * 4 + g) * 4);
  const unsigned stride = layer ? 0u : (unsigned)(BATCH * 16 * 4);
  const unsigned maxofs = (unsigned)(WS_XG_F * 4) + XG_BYTES - 4u;

  float* sp = out + b * 4 + j;         // stored by (layer==1, g==0) lanes

  float A0 = 0.f, A1 = 0.f, A2 = 0.f, A3 = 0.f;   // own-layer h broadcast
  float Bb0[4] = {0.f, 0.f, 0.f, 0.f};            // cross-layer ship, even iters
  float Bb1[4] = {0.f, 0.f, 0.f, 0.f};            // cross-layer ship, odd iters
  float cs = 0.f;                                  // cell state * 2log2e

  auto ld1 = [&](unsigned o) -> float {
    o = (o > maxofs) ? maxofs : o;
    return *(const float*)((const char*)wsr + o);
  };

  float buf[8];
#pragma unroll
  for (int p = 0; p < 8; ++p) { buf[p] = ld1(ofs); ofs += stride; }

  // One recurrence step. B (consumed, then overwritten with the new ship,
  // to be consumed 2 iterations later).
  auto step = [&](const float base, float (&B)[4], int t, bool do_store) {
    // B-side partial sum: B is ready at step start -> off the critical path
    float pre = fmaf(B[0], wB[0], base);
    pre = fmaf(B[1], wB[1], pre);
    float pre2 = fmaf(B[3], wB[3], B[2] * wB[2]);
    pre += pre2;

    // A-side balanced tree (critical path: 3 deep after A broadcast)
    float m01 = fmaf(A1, wA[1], A0 * wA[0]);
    float m23 = fmaf(A3, wA[3], A2 * wA[2]);
    const float P = (m01 + m23) + pre;

    // one activation for the whole wave (1 exp2 + 1 rcp)
    const float r   = rcp_(1.f + ex2_(P));
    const float act = fmaf(ka, r, kb);

    // gather this unit's 4 gates within the quad
    const float vi = dppf<0x00>(act), vf = dppf<0x55>(act),
                vg = dppf<0xAA>(act), vo = dppf<0xFF>(act);

    // cs = sigma(f)*cs + sigma(i)*(2log2e*tanh(g));  tanh(c)=1-2/(1+2^cs)
    cs = fmaf(vf, cs, vi * vg);
    const float tc = fmaf(-2.f, rcp_(1.f + ex2_(cs)), 1.f);
    const float hq = vo * tc;          // h of own quad's unit, all 4 lanes

    // own-layer broadcast via DPP compositions (VALU pipe, ~2x4cy deep):
    //   A1 = ^4 = qp_rev(half_mirror), A2 = ^8 = half_mirror(mirror),
    //   A3 = ^12 = qp_rev(mirror)
    const float hm_ = dppf<ROW_HM>(hq);
    const float rm_ = dppf<ROW_MIR>(hq);
    A0 = hq;
    A1 = dppf<QP_REV>(hm_);
    A2 = dppf<ROW_HM>(rm_);
    A3 = dppf<QP_REV>(rm_);

    // cross-layer ship (^16): consumed 2 iterations from now -> the
    // ds_swizzle's LDS latency is fully hidden by a whole step (~300cy).
    B[0] = swzf<0x401F>(A0);
    B[1] = swzf<0x401F>(A1);
    B[2] = swzf<0x401F>(A2);
    B[3] = swzf<0x401F>(A3);

    if (do_store) {
      if (layer && g == 0) *sp = (t < len) ? hq : 0.f;
      sp += BATCH * 4;
    }
  };

  // Priming iterations i=0,1: layer0 computes t=0,1 (real); layer1 computes
  // garbage (its valid t=0 starts at i=2, consuming y0(0) shipped at i=0).
  // Reset layer1's state after; its garbage ships land in layer0's B (wB=0).
  step(buf[0], Bb0, -2, false); buf[0] = ld1(ofs); ofs += stride;
  step(buf[1], Bb1, -1, false); buf[1] = ld1(ofs); ofs += stride;
  if (layer) { cs = 0.f; A0 = 0.f; A1 = 0.f; A2 = 0.f; A3 = 0.f; }

  // Main: iterations i=2..2049 (2048 total). layer0 computes t=i (clamped
  // reads past the end), layer1 computes+stores t=i-2. Pair-unrolled so the
  // buf[] and B-set indices stay compile-time constants (stride 2 x unroll 4
  // = 8 = prefetch depth).
  int t = 0;
#pragma unroll 4
  for (int i = 2; i < LSEQ + 2; i += 2) {
    step(buf[i & 7], Bb0, t, true);
    buf[i & 7] = ld1(ofs); ofs += stride;
    step(buf[(i + 1) & 7], Bb1, t + 1, true);
    buf[(i + 1) & 7] = ld1(ofs); ofs += stride;
    t += 2;
  }
}

extern "C" void kernel_launch(void* const* d_in, const int* in_sizes, int n_in,
                              void* d_out, int out_size, void* d_ws, size_t ws_size,
                              hipStream_t stream) {
  const float* x    = (const float*)d_in[0];
  const int*   lens = (const int*)d_in[1];
  const float* Wih0 = (const float*)d_in[2];
  const float* Whh0 = (const float*)d_in[3];
  const float* bih0 = (const float*)d_in[4];
  const float* bhh0 = (const float*)d_in[5];
  const float* Wih1 = (const float*)d_in[6];
  const float* Whh1 = (const float*)d_in[7];
  const float* bih1 = (const float*)d_in[8];
  const float* bhh1 = (const float*)d_in[9];
  float* ws  = (float*)d_ws;
  float* out = (float*)d_out;

  xg_kernel<<<(LSEQ * BATCH) / RPB, TPB1, 0, stream>>>(
      x, Wih0, bih0, bhh0, bih1, bhh1, ws);
  lstm_rec<<<BATCH / 2, 64, 0, stream>>>(
      ws, lens, Whh0, Whh1, Wih1, out);
}

// Round 3
// 715.981 us; speedup vs baseline: 1.1132x; 1.1132x over previous
//
#include <hip/hip_runtime.h>

// 2-layer LSTM (PyTorch gate order i,f,g,o), L=2048, B=512, INPUT=78, H=4.
//
// Kernel 1 (R8 rewrite): input projection, pure-DS hot loop.
//   Old version read Wih0 via uniform s_loads inside the k-loop; SMEM results
//   return out-of-order so every xk ds_read wait forced lgkmcnt(0), draining
//   16 weight loads per iteration at 2 waves/SIMD occupancy. Now weights are
//   staged once per block into LDS, TRANSPOSED and PRESCALED:
//     wT[k][j*4+g] = s(g) * Wih0[(g*4+j)*78 + k],  s(g)= g==2 ? 2log2e : -log2e
//   Hot loop per k-pair: 2x ds_read_b64 (own x row) + 8x ds_read_b128
//   (uniform -> broadcast, conflict-free) + 16 v_pk_fma_f32. Each lane
//   computes 2 rows (tid, tid+64) to amortize weight reads. 64-thread blocks,
//   128 rows/block, LDS 39936(x)+4992(w) B -> 3 blocks/CU. Bias+scale folded
//   into acc init; epilogue = 4 float4 stores/row in [j][g] interleave.
// Kernel 2 (reverted to R6, measured 259us): 16 lanes per (batch, layer),
//   one gate per lane, 1 activation + 1 tanh(c) per step (4 trans ops),
//   quad_perm gate gather, 7 parallel ds_swizzle XORs for h broadcast +
//   layer ship, 1-step layer skew, prefetch depth 8, unroll 8.
//   (R7's DPP-composition + 2-step-skew variant regressed: issue went up,
//   stall unchanged -> swizzle latency was not the dominant stall.)
//
// ws: [0,64) bias1_scaled | [20480 B, 20480+64MiB) xg0.

#define LSEQ  2048
#define BATCH 512
#define NIN   78
#define LOG2E 1.4426950408889634f

#define WS_BIAS_F  0
#define WS_XG_F    5120
#define XG_BYTES   ((unsigned)LSEQ * BATCH * 16u * 4u)

#define RPB  128

typedef __attribute__((ext_vector_type(2))) float vf2;

__device__ __forceinline__ float rcp_(float x) { return __builtin_amdgcn_rcpf(x); }
__device__ __forceinline__ float ex2_(float x) { return __builtin_amdgcn_exp2f(x); }
__device__ __forceinline__ vf2 pkfma(vf2 a, vf2 b, vf2 c) {
  return __builtin_elementwise_fma(a, b, c);
}

template<int CTRL>
__device__ __forceinline__ float dppf(float x) {
  int r = __builtin_amdgcn_update_dpp(0, __builtin_bit_cast(int, x), CTRL, 0xf, 0xf, false);
  return __builtin_bit_cast(float, r);
}
template<int PAT>
__device__ __forceinline__ float swzf(float x) {
  int r = __builtin_amdgcn_ds_swizzle(__builtin_bit_cast(int, x), PAT);
  return __builtin_bit_cast(float, r);
}

// ---------------- kernel 1: input projection (pure-DS hot loop) ----------
__global__ __launch_bounds__(64) void xg_kernel(
    const float* __restrict__ x, const float* __restrict__ Wih0,
    const float* __restrict__ bih0, const float* __restrict__ bhh0,
    const float* __restrict__ bih1, const float* __restrict__ bhh1,
    float* __restrict__ ws)
{
  __shared__ float xs[RPB * NIN];      // 39936 B, linear (row stride 78)
  __shared__ float wT[NIN][16];        // 4992 B: [k][j*4+g], prescaled
  const int tid = threadIdx.x;
  const int r0  = blockIdx.x * RPB;

  if (blockIdx.x == 0 && tid < 16) {   // prescaled layer-1 bias [j*4+g]
    const int j = tid >> 2, g = tid & 3, row = j + 4 * g;
    const float s = (g == 2) ? 2.f * LOG2E : -LOG2E;
    ws[WS_BIAS_F + tid] = s * (bih1[row] + bhh1[row]);
  }

  // stage prescaled transposed weights (tiny, L2-hot across blocks)
  for (int i = tid; i < NIN * 16; i += 64) {
    const int k = i >> 4, a = i & 15;
    const int j = a >> 2, g = a & 3;
    const float s = (g == 2) ? 2.f * LOG2E : -LOG2E;
    wT[k][a] = s * Wih0[(g * 4 + j) * NIN + k];
  }

  // stage 128 x-rows, coalesced float4
  const float4* gx = (const float4*)(x + (size_t)r0 * NIN);
  float4* ls = (float4*)xs;
#pragma unroll
  for (int i = 0; i < (RPB * NIN / 4) / 64; ++i)   // 39 iters exactly
    ls[tid + i * 64] = gx[tid + i * 64];
  __syncthreads();

  // acc[a], a = j*4+g (output-interleaved order), bias+scale folded in
  vf2 accA[8], accB[8];
#pragma unroll
  for (int p = 0; p < 8; ++p) {
    float bv[2];
#pragma unroll
    for (int u = 0; u < 2; ++u) {
      const int a = 2 * p + u, j = a >> 2, g = a & 3;
      const float s = (g == 2) ? 2.f * LOG2E : -LOG2E;
      bv[u] = s * (bih0[g * 4 + j] + bhh0[g * 4 + j]);
    }
    accA[p] = vf2{ bv[0], bv[1] };
    accB[p] = vf2{ bv[0], bv[1] };
  }

  const float* xrA = xs + tid * NIN;          // row base 8B-aligned (312*tid)
  const float* xrB = xs + (tid + 64) * NIN;

#pragma unroll 3
  for (int k2 = 0; k2 < NIN / 2; ++k2) {      // 39 k-pairs
    const vf2 xA2 = *(const vf2*)(xrA + 2 * k2);
    const vf2 xB2 = *(const vf2*)(xrB + 2 * k2);
    const float4* wk0 = (const float4*)&wT[2 * k2][0];
    const float4* wk1 = (const float4*)&wT[2 * k2 + 1][0];
    const vf2 xa0 = vf2{ xA2.x, xA2.x }, xa1 = vf2{ xA2.y, xA2.y };
    const vf2 xb0 = vf2{ xB2.x, xB2.x }, xb1 = vf2{ xB2.y, xB2.y };
#pragma unroll
    for (int q = 0; q < 4; ++q) {
      const float4 w0 = wk0[q], w1 = wk1[q];
      const vf2 w0a = vf2{ w0.x, w0.y }, w0b = vf2{ w0.z, w0.w };
      const vf2 w1a = vf2{ w1.x, w1.y }, w1b = vf2{ w1.z, w1.w };
      accA[2 * q]     = pkfma(xa0, w0a, accA[2 * q]);
      accA[2 * q + 1] = pkfma(xa0, w0b, accA[2 * q + 1]);
      accA[2 * q]     = pkfma(xa1, w1a, accA[2 * q]);
      accA[2 * q + 1] = pkfma(xa1, w1b, accA[2 * q + 1]);
      accB[2 * q]     = pkfma(xb0, w0a, accB[2 * q]);
      accB[2 * q + 1] = pkfma(xb0, w0b, accB[2 * q + 1]);
      accB[2 * q]     = pkfma(xb1, w1a, accB[2 * q]);
      accB[2 * q + 1] = pkfma(xb1, w1b, accB[2 * q + 1]);
    }
  }

  float* oA = ws + WS_XG_F + (size_t)(r0 + tid) * 16;
  float* oB = ws + WS_XG_F + (size_t)(r0 + 64 + tid) * 16;
#pragma unroll
  for (int q = 0; q < 4; ++q) {
    *(float4*)(oA + q * 4) = make_float4(accA[2 * q].x, accA[2 * q].y,
                                         accA[2 * q + 1].x, accA[2 * q + 1].y);
    *(float4*)(oB + q * 4) = make_float4(accB[2 * q].x, accB[2 * q].y,
                                         accB[2 * q + 1].x, accB[2 * q + 1].y);
  }
}

// ---------------- kernel 2: recurrence (R6, measured 259us) --------------
__global__ __launch_bounds__(64) void lstm_rec(
    const float* __restrict__ wsr,
    const int* __restrict__ lens,
    const float* __restrict__ Whh0, const float* __restrict__ Whh1,
    const float* __restrict__ Wih1,
    float* __restrict__ out)
{
  const int lane  = threadIdx.x;
  const int g     = lane & 3;          // gate: 0=i 1=f 2=g 3=o
  const int j     = (lane >> 2) & 3;   // hidden unit
  const int layer = (lane >> 4) & 1;
  const int b     = blockIdx.x * 2 + (lane >> 5);

  const float sg = (g == 2) ? 2.f * LOG2E : -LOG2E;   // pre-activation scale
  // act = ka*rcp(1+exp2(P)) + kb : sigmoid lanes -> sigma; g lane -> 2log2e*tanh
  const float ka = (g == 2) ? -4.f * LOG2E : 1.f;
  const float kb = (g == 2) ?  2.f * LOG2E : 0.f;

  const int row4 = (g * 4 + j) * 4;    // PyTorch row = gate*4 + unit
  const float* whh = layer ? Whh1 : Whh0;
  float wA[4], wB[4];
#pragma unroll
  for (int m = 0; m < 4; ++m) {        // A_m = h[j^m] (ds_swizzle xor mapping)
    wA[m] = sg * whh[row4 + (j ^ m)];
    wB[m] = layer ? sg * Wih1[row4 + (j ^ m)] : 0.f;
  }
  const int len = lens[b];

  // layer0 lanes stream xg0[t][b][j*4+g]; layer1 lanes "stream" their own
  // prescaled bias dword (stride 0) so the dot base needs no per-iter select.
  unsigned ofs = layer ? (unsigned)((j * 4 + g) * 4)
                       : (unsigned)(WS_XG_F * 4 + (b * 16 + j * 4 + g) * 4);
  const unsigned stride = layer ? 0u : (unsigned)(BATCH * 16 * 4);
  const unsigned maxofs = (unsigned)(WS_XG_F * 4) + XG_BYTES - 4u;

  float* sp = out + b * 4 + j;         // stored by (layer==1, g==0) lanes

  float A0 = 0.f, A1 = 0.f, A2 = 0.f, A3 = 0.f;   // own-layer h broadcast
  float B0 = 0.f, B1 = 0.f, B2 = 0.f, B3 = 0.f;   // other-layer h (y0 feed)
  float cs = 0.f;                                  // cell state * 2log2e

  auto ld1 = [&](unsigned o) -> float {
    o = (o > maxofs) ? maxofs : o;
    return *(const float*)((const char*)wsr + o);
  };

  float buf[8];
#pragma unroll
  for (int p = 0; p < 8; ++p) { buf[p] = ld1(ofs); ofs += stride; }

  auto step = [&](const float base, int t, bool do_store) {
    // gate pre-activation: base + sum_m A_m*wA[m] + sum_m B_m*wB[m]
    float p0 = fmaf(A0, wA[0], base);
    p0 = fmaf(A1, wA[1], p0);
    float p1 = A2 * wA[2];
    p1 = fmaf(A3, wA[3], p1);
    float p2 = fmaf(B0, wB[0], B1 * wB[1]);
    float p3 = fmaf(B2, wB[2], B3 * wB[3]);
    const float P = (p0 + p1) + (p2 + p3);

    // one activation for the whole wave (1 exp2 + 1 rcp)
    const float r   = rcp_(1.f + ex2_(P));
    const float act = fmaf(ka, r, kb);

    // gather this unit's 4 gates within the quad
    const float vi = dppf<0x00>(act), vf = dppf<0x55>(act),
                vg = dppf<0xAA>(act), vo = dppf<0xFF>(act);

    // cs = sigma(f)*cs + sigma(i)*(2log2e*tanh(g));  tanh(c)=1-2/(1+2^cs)
    cs = fmaf(vf, cs, vi * vg);
    const float tc = fmaf(-2.f, rcp_(1.f + ex2_(cs)), 1.f);
    const float hq = vo * tc;          // h of own quad's unit, all 4 lanes

    // broadcast across units + ship across layers: 7 parallel xor swizzles
    A0 = hq;
    A1 = swzf<0x101F>(hq);             // lane ^ 4   -> h[j^1]
    A2 = swzf<0x201F>(hq);             // lane ^ 8   -> h[j^2]
    A3 = swzf<0x301F>(hq);             // lane ^ 12  -> h[j^3]
    B0 = swzf<0x401F>(hq);             // lane ^ 16  -> other layer h[j]
    B1 = swzf<0x501F>(hq);             // lane ^ 20
    B2 = swzf<0x601F>(hq);             // lane ^ 24
    B3 = swzf<0x701F>(hq);             // lane ^ 28

    if (do_store) {
      if (layer && g == 0) *sp = (t < len) ? hq : 0.f;
      sp += BATCH * 4;
    }
  };

  // iteration 0: layer0 computes t=0; layer1 output is garbage -> reset its
  // state but KEEP B (= shipped h0(t=0), the input for layer1's t=0).
  step(buf[0], -1, false);
  if (layer) { cs = 0.f; A0 = 0.f; A1 = 0.f; A2 = 0.f; A3 = 0.f; }
  buf[0] = ld1(ofs); ofs += stride;

  // iteration k: layer0 computes t=k, layer1 computes (and stores) t=k-1
#pragma unroll 8
  for (int k = 1; k <= LSEQ; ++k) {
    step(buf[k & 7], k - 1, true);
    buf[k & 7] = ld1(ofs); ofs += stride;
  }
}

extern "C" void kernel_launch(void* const* d_in, const int* in_sizes, int n_in,
                              void* d_out, int out_size, void* d_ws, size_t ws_size,
                              hipStream_t stream) {
  const float* x    = (const float*)d_in[0];
  const int*   lens = (const int*)d_in[1];
  const float* Wih0 = (const float*)d_in[2];
  const float* Whh0 = (const float*)d_in[3];
  const float* bih0 = (const float*)d_in[4];
  const float* bhh0 = (const float*)d_in[5];
  const float* Wih1 = (const float*)d_in[6];
  const float* Whh1 = (const float*)d_in[7];
  const float* bih1 = (const float*)d_in[8];
  const float* bhh1 = (const float*)d_in[9];
  float* ws  = (float*)d_ws;
  float* out = (float*)d_out;

  xg_kernel<<<(LSEQ * BATCH) / RPB, 64, 0, stream>>>(
      x, Wih0, bih0, bhh0, bih1, bhh1, ws);
  lstm_rec<<<BATCH / 2, 64, 0, stream>>>(
      ws, lens, Whh0, Whh1, Wih1, out);
}